// Round 6
// baseline (230.925 us; speedup 1.0000x reference)
//
#include <hip/hip_runtime.h>

// Problem constants (fixed by setup_inputs):
//   img:  [B=4, C=1, D=64, H=192, W=192]  fp32
//   flow: [B=4, 3,   D=64, H=192, W=192]  fp32
//   out:  [B=4, C=1, D=64, H=192, W=192]  fp32
#define B_  4
#define D_  64
#define H_  192
#define W_  192
#define HW_ (H_ * W_)
#define DHW_ (D_ * H_ * W_)

// Persistent z-marching workgroup: owns a (b, X:TX, Y:TY) column, marches
// z = 0..63 with a 16-slot LDS ring holding the 9 active planes [z-4, z+4]
// of a SX x SY window. Per step exactly ONE new plane is staged (prefetch
// to regs before compute, ds_write + single barrier after) -> z-halo cost
// amortizes to zero; staging amp = (64*12)/(48*4) = 4 floats/output, L2-fed.
//   window x: [X-8, X+55]  (SX=64, Xs multiple of 4 -> aligned f4 rows,
//             192 chunks/plane == TPB: one f4 per thread per plane)
//   window y: [Y-4, Y+7]   (SY=12)
//   ring z:   [z-4, z+4]   (NP=9 of SLOTS=16; slot = plane & 15)
// Fallback (halo miss, ~7e-4/sample): exact global pair-loads, exec-masked.
#define TX 48
#define TY 4
#define SX 64
#define SY 12
#define NP 9
#define SLOTS 16
#define RS 64                  // LDS row stride (floats); RS%32==0 -> bank = x offset
#define PS (SY * RS)           // 768 floats per slot-plane
#define LDSF (SLOTS * PS)      // 12288 floats = 48 KB -> 3 wg/CU (144 KB < 160 KB)
#define TPB (TX * TY)          // 192 threads = 3 waves
#define NWGX (W_ / TX)         // 4
#define NWGY (H_ / TY)         // 48
#define NWG (B_ * NWGY * NWGX) // 768 workgroups = exactly 3 per CU, all co-resident

typedef float f4 __attribute__((ext_vector_type(4)));
typedef float f2 __attribute__((ext_vector_type(2)));
typedef f2 f2u __attribute__((aligned(4)));

__global__ __launch_bounds__(TPB) void warp3d_kernel(
    const float* __restrict__ img,
    const float* __restrict__ flow,
    float* __restrict__ out)
{
    __shared__ float lds[LDSF];

    int wg = blockIdx.x;
    int b  = wg / (NWGY * NWGX);
    int rr = wg - b * (NWGY * NWGX);
    int Yt = rr / NWGX;
    int Xt = rr - Yt * NWGX;
    int X = Xt * TX, Y = Yt * TY;
    int Xs = min(max(X - 8, 0), W_ - SX);   // {0,40,88,128}: 16B-aligned rows
    int Ys = min(max(Y - 4, 0), H_ - SY);

    const float* im = img + (size_t)b * DHW_;
    int t = threadIdx.x;

    // staging: thread t owns f4 chunk (row t>>4, col (t&15)*4) of every plane
    int srow = t >> 4;                      // 0..11
    int scol = (t & 15) << 2;               // 0..60
    const float* sbase = im + (Ys + srow) * W_ + Xs + scol;
    float* lbase = lds + srow * RS + scol;

    // preload planes 0..8 (initial window for z=0..4)
#pragma unroll
    for (int p = 0; p < NP; ++p) {
        f4 v = *(const f4*)(sbase + (size_t)p * HW_);
        *(f4*)(lbase + (p & (SLOTS - 1)) * PS) = v;
    }
    __syncthreads();

    int ty = t / TX;
    int tx = t - ty * TX;
    int x = X + tx, y = Y + ty;

    const float* fl = flow + (size_t)b * 3 * DHW_ + (size_t)y * W_ + x;
    float* op = out + (size_t)b * DHW_ + (size_t)y * W_ + x;

    const float sxc = (float)W_ / (float)(W_ - 1);
    const float syc = (float)H_ / (float)(H_ - 1);
    const float szc = (float)D_ / (float)(D_ - 1);

    for (int z = 0; z < D_; ++z) {
        // prefetch next plane (z+5, needed from step z+1 on) into registers
        bool do_stage = (z >= 4) && (z <= 58);
        f4 pv;
        if (do_stage)
            pv = *(const f4*)(sbase + (size_t)(z + 5) * HW_);

        float fx = __builtin_nontemporal_load(fl);
        float fy = __builtin_nontemporal_load(fl + DHW_);
        float fz = __builtin_nontemporal_load(fl + 2 * DHW_);

        float ix = ((float)x + fx) * sxc - 0.5f;
        float iy = ((float)y + fy) * syc - 0.5f;
        float iz = ((float)z + fz) * szc - 0.5f;
        ix = fminf(fmaxf(ix, 0.0f), (float)(W_ - 1));
        iy = fminf(fmaxf(iy, 0.0f), (float)(H_ - 1));
        iz = fminf(fmaxf(iz, 0.0f), (float)(D_ - 1));

        float x0f = floorf(ix), y0f = floorf(iy), z0f = floorf(iz);
        float wx = ix - x0f, wy = iy - y0f, wz = iz - z0f;
        int x0 = (int)x0f, y0 = (int)y0f, z0 = (int)z0f;
        int xb = min(x0, W_ - 2);
        int hi = x0 - xb;                   // 1 only when x0 == W-1
        int y1 = min(y0 + 1, H_ - 1);
        int z1 = min(z0 + 1, D_ - 1);

        int wlo = min(max(z - 4, 0), D_ - NP);
        bool val = (xb >= Xs) & (xb <= Xs + SX - 2) &
                   (y0 >= Ys) & (y1 <= Ys + SY - 1) &
                   (z0 >= wlo) & (z1 <= wlo + NP - 1);

        float v000, v001, v010, v011, v100, v101, v110, v111;
        if (val) {
            int xo = xb - Xs;
            int a00 = ((z0 & (SLOTS - 1)) * SY + (y0 - Ys)) * RS + xo;
            int a01 = ((z0 & (SLOTS - 1)) * SY + (y1 - Ys)) * RS + xo;
            int a10 = ((z1 & (SLOTS - 1)) * SY + (y0 - Ys)) * RS + xo;
            int a11 = ((z1 & (SLOTS - 1)) * SY + (y1 - Ys)) * RS + xo;
            v000 = lds[a00]; v001 = lds[a00 + 1];
            v010 = lds[a01]; v011 = lds[a01 + 1];
            v100 = lds[a10]; v101 = lds[a10 + 1];
            v110 = lds[a11]; v111 = lds[a11 + 1];
        } else {
            // exact fallback (~7e-4 of samples), exec-masked
            f2 p00 = *(const f2u*)(im + (z0 * H_ + y0) * W_ + xb);
            f2 p01 = *(const f2u*)(im + (z0 * H_ + y1) * W_ + xb);
            f2 p10 = *(const f2u*)(im + (z1 * H_ + y0) * W_ + xb);
            f2 p11 = *(const f2u*)(im + (z1 * H_ + y1) * W_ + xb);
            v000 = p00.x; v001 = p00.y;
            v010 = p01.x; v011 = p01.y;
            v100 = p10.x; v101 = p10.y;
            v110 = p11.x; v111 = p11.y;
        }
        if (hi) { v000 = v001; v010 = v011; v100 = v101; v110 = v111; }

        float c00 = v000 + wx * (v001 - v000);
        float c01 = v010 + wx * (v011 - v010);
        float c10 = v100 + wx * (v101 - v100);
        float c11 = v110 + wx * (v111 - v110);
        float c0 = c00 + wy * (c01 - c00);
        float c1 = c10 + wy * (c11 - c10);
        __builtin_nontemporal_store(c0 + wz * (c1 - c0), op);

        if (do_stage) {
            // target slot (z+5)&15 held plane z-11 (< wlo) -> no reader at
            // step z, so no pre-write barrier needed; one barrier makes the
            // write visible before step z+1's reads.
            *(f4*)(lbase + ((z + 5) & (SLOTS - 1)) * PS) = pv;
            __syncthreads();
        }
        fl += HW_; op += HW_;
    }
}

extern "C" void kernel_launch(void* const* d_in, const int* in_sizes, int n_in,
                              void* d_out, int out_size, void* d_ws, size_t ws_size,
                              hipStream_t stream) {
    const float* img  = (const float*)d_in[0];
    const float* flow = (const float*)d_in[1];
    float* out = (float*)d_out;

    warp3d_kernel<<<NWG, TPB, 0, stream>>>(img, flow, out);
}

// Round 7
// 210.417 us; speedup vs baseline: 1.0975x; 1.0975x over previous
//
#include <hip/hip_runtime.h>

// Problem constants (fixed by setup_inputs):
//   img:  [B=4, C=1, D=64, H=192, W=192]  fp32
//   flow: [B=4, 3,   D=64, H=192, W=192]  fp32
//   out:  [B=4, C=1, D=64, H=192, W=192]  fp32
#define B_  4
#define D_  64
#define H_  192
#define W_  192
#define HW_ (H_ * W_)
#define DHW_ (D_ * H_ * W_)

// R4's proven stage-once/one-barrier shape, retiled for 2 wg/CU overlap:
//   outputs per wg: 64 x 8 x 4 (x,y,z) = 2048, VEC=2 -> TPB=1024 (16 waves)
//   window: 80 x 16 x 12 = 61,440 B LDS -> 2 wg/CU, 32 waves = 100% occ.
// Cross-wg overlap hides one wg's staging under the other's compute (R4's
// 120 KB -> 1 wg/CU serialized the phases; that was the dominant loss).
// Halos: x +-8, y +-4, z -4/+4 past tile ends -> fallback ~1e-4/sample
// (<1% of waves take the exec-masked exact global path).
#define TX 64
#define TY 8
#define TZ 4
#define SX 80
#define SY 16
#define SZ 12
#define PS (SY * SX)             // 1280 floats per staged plane
#define LDSF (SZ * PS)           // 15360 floats = 61,440 B
#define NCH (LDSF / 4)           // 3840 f4 chunks
#define CPP (PS / 4)             // 320 chunks per plane
#define CPR (SX / 4)             // 20 chunks per row
#define VEC 2
#define TPB (TX * TY * TZ / VEC) // 1024 threads = 16 waves
#define NWGX (W_ / TX)           // 3
#define NWGY (H_ / TY)           // 24
#define NWGZ (D_ / TZ)           // 16
#define NWG (B_ * NWGZ * NWGY * NWGX)  // 4608

typedef float f4 __attribute__((ext_vector_type(4)));
typedef float f2 __attribute__((ext_vector_type(2)));
typedef f2 f2u __attribute__((aligned(4)));

__global__ __launch_bounds__(TPB, 8) void warp3d_kernel(
    const float* __restrict__ img,
    const float* __restrict__ flow,
    float* __restrict__ out)
{
    __shared__ float lds[LDSF];

    int wg = blockIdx.x;
    int b   = wg / (NWGZ * NWGY * NWGX);
    int rr  = wg - b * (NWGZ * NWGY * NWGX);
    int zt  = rr / (NWGY * NWGX);
    int rr2 = rr - zt * (NWGY * NWGX);
    int yt  = rr2 / NWGX;
    int xt  = rr2 - yt * NWGX;
    int X = xt * TX, Y = yt * TY, Z = zt * TZ;
    int Xs = min(max(X - 8, 0), W_ - SX);   // {0,56,112}: 16B-aligned
    int Ys = min(max(Y - 4, 0), H_ - SY);
    int Zs = min(max(Z - 4, 0), D_ - SZ);

    const float* im = img + (size_t)b * DHW_;
    int t = threadIdx.x;

    // ---- stage 80x16x12 window (f4 chunks; rows are 20 aligned chunks) ----
    for (int c = t; c < NCH; c += TPB) {
        int j   = c / CPP;                 // plane 0..11
        int rem = c - j * CPP;
        int row = rem / CPR;               // 0..15
        int col = rem - row * CPR;         // 0..19
        f4 v = *(const f4*)(im + (size_t)(Zs + j) * HW_
                               + (size_t)(Ys + row) * W_ + Xs + col * 4);
        *(f4*)(lds + c * 4) = v;           // lds float-addr = 4c (layout identity)
    }
    __syncthreads();

    // ---- this thread's 2 outputs ----
    int o  = t * VEC;
    int x  = X + (o % TX);
    int q  = o / TX;                       // 0..31
    int y  = Y + (q % TY);
    int z  = Z + (q / TY);

    size_t nbase = (size_t)b * DHW_ + ((size_t)z * H_ + y) * W_ + x;
    const float* fl = flow + (size_t)b * 3 * DHW_ + ((size_t)z * H_ + y) * W_ + x;
    f2 fx = __builtin_nontemporal_load((const f2u*)fl);
    f2 fy = __builtin_nontemporal_load((const f2u*)(fl + DHW_));
    f2 fz = __builtin_nontemporal_load((const f2u*)(fl + 2 * DHW_));

    const float sxc = (float)W_ / (float)(W_ - 1);
    const float syc = (float)H_ / (float)(H_ - 1);
    const float szc = (float)D_ / (float)(D_ - 1);

    f2 res;
#pragma unroll
    for (int i = 0; i < VEC; ++i) {
        float ix = ((float)(x + i) + fx[i]) * sxc - 0.5f;
        float iy = ((float)y + fy[i]) * syc - 0.5f;
        float iz = ((float)z + fz[i]) * szc - 0.5f;
        ix = fminf(fmaxf(ix, 0.0f), (float)(W_ - 1));
        iy = fminf(fmaxf(iy, 0.0f), (float)(H_ - 1));
        iz = fminf(fmaxf(iz, 0.0f), (float)(D_ - 1));

        float x0f = floorf(ix), y0f = floorf(iy), z0f = floorf(iz);
        float wx = ix - x0f, wy = iy - y0f, wz = iz - z0f;
        int x0 = (int)x0f, y0 = (int)y0f, z0 = (int)z0f;
        int xb = min(x0, W_ - 2);
        int hi = x0 - xb;                  // 1 only when x0 == W-1
        int y1 = min(y0 + 1, H_ - 1);
        int z1 = min(z0 + 1, D_ - 1);

        bool val = (xb >= Xs) & (xb <= Xs + SX - 2) &
                   (y0 >= Ys) & (y1 <= Ys + SY - 1) &
                   (z0 >= Zs) & (z1 <= Zs + SZ - 1);

        float v000, v001, v010, v011, v100, v101, v110, v111;
        if (val) {
            int xo = xb - Xs;
            int a00 = ((z0 - Zs) * SY + (y0 - Ys)) * SX + xo;
            int a01 = ((z0 - Zs) * SY + (y1 - Ys)) * SX + xo;
            int a10 = ((z1 - Zs) * SY + (y0 - Ys)) * SX + xo;
            int a11 = ((z1 - Zs) * SY + (y1 - Ys)) * SX + xo;
            v000 = lds[a00]; v001 = lds[a00 + 1];
            v010 = lds[a01]; v011 = lds[a01 + 1];
            v100 = lds[a10]; v101 = lds[a10 + 1];
            v110 = lds[a11]; v111 = lds[a11 + 1];
        } else {
            // exact fallback (~1e-4 of samples), exec-masked
            f2 p00 = *(const f2u*)(im + (z0 * H_ + y0) * W_ + xb);
            f2 p01 = *(const f2u*)(im + (z0 * H_ + y1) * W_ + xb);
            f2 p10 = *(const f2u*)(im + (z1 * H_ + y0) * W_ + xb);
            f2 p11 = *(const f2u*)(im + (z1 * H_ + y1) * W_ + xb);
            v000 = p00.x; v001 = p00.y;
            v010 = p01.x; v011 = p01.y;
            v100 = p10.x; v101 = p10.y;
            v110 = p11.x; v111 = p11.y;
        }
        if (hi) { v000 = v001; v010 = v011; v100 = v101; v110 = v111; }

        float c00 = v000 + wx * (v001 - v000);
        float c01 = v010 + wx * (v011 - v010);
        float c10 = v100 + wx * (v101 - v100);
        float c11 = v110 + wx * (v111 - v110);
        float c0 = c00 + wy * (c01 - c00);
        float c1 = c10 + wy * (c11 - c10);
        res[i] = c0 + wz * (c1 - c0);
    }
    __builtin_nontemporal_store(res, (f2*)(out + nbase));
}

extern "C" void kernel_launch(void* const* d_in, const int* in_sizes, int n_in,
                              void* d_out, int out_size, void* d_ws, size_t ws_size,
                              hipStream_t stream) {
    const float* img  = (const float*)d_in[0];
    const float* flow = (const float*)d_in[1];
    float* out = (float*)d_out;

    warp3d_kernel<<<NWG, TPB, 0, stream>>>(img, flow, out);
}